// Round 3
// baseline (83.314 us; speedup 1.0000x reference)
//
#include <hip/hip_runtime.h>

#define EB_D 128
#define EB_CHUNKS_PER_ROW (EB_D / 4)   // 32 float4 chunks per row

// Kernel 1: count[v] = multiplicity of v in eb_input (int32 indices).
// Vectorized int4 loads; global atomics into a 400 KB L2-resident table.
__global__ __launch_bounds__(256) void eb_count_kernel(
    const int* __restrict__ idx, int n4, int n, int* __restrict__ count)
{
    const int stride = gridDim.x * blockDim.x;
    const int4* idx4 = (const int4*)idx;
    for (int i = blockIdx.x * blockDim.x + threadIdx.x; i < n4; i += stride) {
        const int4 v = idx4[i];
        atomicAdd(&count[v.x], 1);
        atomicAdd(&count[v.y], 1);
        atomicAdd(&count[v.z], 1);
        atomicAdd(&count[v.w], 1);
    }
    // tail (n % 4 != 0) — handled by one thread; N=819200 is divisible, so no-op
    if (blockIdx.x == 0 && threadIdx.x == 0) {
        for (int i = n4 * 4; i < n; ++i) atomicAdd(&count[idx[i]], 1);
    }
}

// Kernel 2: out = sum_v count[v] * (5*sum(W0[v,:]) + 10*sum(W1[v,:]) + 6*sum(W2[v,:]))
// Pure streaming reduce over all three tables as flat float4 arrays.
// Grid-stride, 2-way unrolled: 6 independent float4 loads in flight per thread.
__global__ __launch_bounds__(256) void eb_scan_kernel(
    const float4* __restrict__ W0,
    const float4* __restrict__ W1,
    const float4* __restrict__ W2,
    const int* __restrict__ count,
    float* __restrict__ out,
    int nchunks)
{
    const int stride = gridDim.x * blockDim.x;
    int i = blockIdx.x * blockDim.x + threadIdx.x;
    float acc = 0.0f;

    for (; i + stride < nchunks; i += 2 * stride) {
        const int j = i + stride;
        const float4 a0 = W0[i], b0 = W1[i], c0 = W2[i];
        const float4 a1 = W0[j], b1 = W1[j], c1 = W2[j];
        const float cf0 = (float)count[i >> 5];   // row v = chunk >> 5
        const float cf1 = (float)count[j >> 5];
        acc += cf0 * (5.0f  * (a0.x + a0.y + a0.z + a0.w)
                    + 10.0f * (b0.x + b0.y + b0.z + b0.w)
                    + 6.0f  * (c0.x + c0.y + c0.z + c0.w));
        acc += cf1 * (5.0f  * (a1.x + a1.y + a1.z + a1.w)
                    + 10.0f * (b1.x + b1.y + b1.z + b1.w)
                    + 6.0f  * (c1.x + c1.y + c1.z + c1.w));
    }
    if (i < nchunks) {
        const float4 a = W0[i], b = W1[i], c = W2[i];
        const float cf = (float)count[i >> 5];
        acc += cf * (5.0f  * (a.x + a.y + a.z + a.w)
                   + 10.0f * (b.x + b.y + b.z + b.w)
                   + 6.0f  * (c.x + c.y + c.z + c.w));
    }

    // Full-wave (64-lane) butterfly reduce.
    #pragma unroll
    for (int m = 32; m >= 1; m >>= 1) acc += __shfl_xor(acc, m, 64);

    __shared__ float wsum[4];
    const int lane = threadIdx.x & 63;
    const int wid  = threadIdx.x >> 6;
    if (lane == 0) wsum[wid] = acc;
    __syncthreads();
    if (threadIdx.x == 0) {
        atomicAdd(out, wsum[0] + wsum[1] + wsum[2] + wsum[3]);
    }
}

extern "C" void kernel_launch(void* const* d_in, const int* in_sizes, int n_in,
                              void* d_out, int out_size, void* d_ws, size_t ws_size,
                              hipStream_t stream) {
    const int* eb_input = (const int*)d_in[0];   // int32 indices
    // d_in[1] = eb_offset: mathematically irrelevant (result sums over all bags).
    const float* W0 = (const float*)d_in[2];
    const float* W1 = (const float*)d_in[3];
    const float* W2 = (const float*)d_in[4];

    const int N = in_sizes[0];
    const int nrows = in_sizes[2] / EB_D;                 // V
    const int nchunks = nrows * EB_CHUNKS_PER_ROW;        // V * 32 float4s

    int* count = (int*)d_ws;                              // V ints = 400 KB
    float* out = (float*)d_out;

    // Zero output and count table each call (graph-capture-safe).
    hipMemsetAsync(out, 0, (size_t)out_size * sizeof(float), stream);
    hipMemsetAsync(count, 0, (size_t)nrows * sizeof(int), stream);

    // Kernel 1: histogram of indices.
    const int n4 = N / 4;
    int blocks1 = (n4 + 255) / 256;
    if (blocks1 > 800) blocks1 = 800;
    eb_count_kernel<<<blocks1, 256, 0, stream>>>(eb_input, n4, N, count);

    // Kernel 2: weighted streaming reduce over the three tables.
    eb_scan_kernel<<<2048, 256, 0, stream>>>(
        (const float4*)W0, (const float4*)W1, (const float4*)W2,
        count, out, nchunks);
}

// Round 4
// 49.077 us; speedup vs baseline: 1.6976x; 1.6976x over previous
//
#include <hip/hip_runtime.h>

#define EB_D 128

// Kernel 1: rowsum[v] = 5*sum(W0[v,:]) + 10*sum(W1[v,:]) + 6*sum(W2[v,:])
// Block = 256 threads = 4 waves; block owns 32 consecutive rows.
// Each wave handles 8 rows as 4 unrolled row-pairs; all 12 float4 loads
// (4 steps x 3 tables) are issued before any reduction -> 12 loads in
// flight per thread for latency/MLP coverage.
__global__ __launch_bounds__(256) void eb_rowsum_kernel(
    const float* __restrict__ W0,
    const float* __restrict__ W1,
    const float* __restrict__ W2,
    float* __restrict__ rowsum,
    int nrows)
{
    const int lane   = threadIdx.x & 63;
    const int wave   = threadIdx.x >> 6;          // 0..3
    const int lane32 = lane & 31;
    const int half   = lane >> 5;                 // 0/1: which row of the pair
    const int rbase  = blockIdx.x * 32 + wave * 8 + half;  // rows rbase+2s, s=0..3

    float4 a[4], b[4], c[4];
    #pragma unroll
    for (int s = 0; s < 4; ++s) {
        const int v = rbase + 2 * s;
        const size_t base = (size_t)v * EB_D;
        a[s] = ((const float4*)(W0 + base))[lane32];
        b[s] = ((const float4*)(W1 + base))[lane32];
        c[s] = ((const float4*)(W2 + base))[lane32];
    }

    #pragma unroll
    for (int s = 0; s < 4; ++s) {
        float sv = 5.0f  * (a[s].x + a[s].y + a[s].z + a[s].w)
                 + 10.0f * (b[s].x + b[s].y + b[s].z + b[s].w)
                 + 6.0f  * (c[s].x + c[s].y + c[s].z + c[s].w);
        // reduce across the 32 lanes of this half-wave
        #pragma unroll
        for (int m = 16; m >= 1; m >>= 1) sv += __shfl_xor(sv, m, 64);
        const int v = rbase + 2 * s;
        if (lane32 == 0 && v < nrows) rowsum[v] = sv;
    }
}

// Kernel 2: out += sum_i rowsum[idx[i]]  (idx int32); int4-vectorized.
__global__ __launch_bounds__(256) void eb_gather_reduce_kernel(
    const int* __restrict__ idx,
    const float* __restrict__ rowsum,
    float* __restrict__ out,
    int n4, int n, int nrows)
{
    const int stride = gridDim.x * blockDim.x;
    const int4* idx4 = (const int4*)idx;
    float acc = 0.0f;
    for (int i = blockIdx.x * blockDim.x + threadIdx.x; i < n4; i += stride) {
        const int4 v = idx4[i];
        float s0 = ((unsigned)v.x < (unsigned)nrows) ? rowsum[v.x] : 0.0f;
        float s1 = ((unsigned)v.y < (unsigned)nrows) ? rowsum[v.y] : 0.0f;
        float s2 = ((unsigned)v.z < (unsigned)nrows) ? rowsum[v.z] : 0.0f;
        float s3 = ((unsigned)v.w < (unsigned)nrows) ? rowsum[v.w] : 0.0f;
        acc += (s0 + s1) + (s2 + s3);
    }
    // tail (N % 4) — N=819200 divisible by 4, so this is a no-op here
    if (blockIdx.x == 0 && threadIdx.x < (n - n4 * 4)) {
        const int v = idx[n4 * 4 + threadIdx.x];
        if ((unsigned)v < (unsigned)nrows) acc += rowsum[v];
    }

    #pragma unroll
    for (int m = 32; m >= 1; m >>= 1) acc += __shfl_xor(acc, m, 64);

    __shared__ float wsum[4];
    const int lane = threadIdx.x & 63;
    const int wid  = threadIdx.x >> 6;
    if (lane == 0) wsum[wid] = acc;
    __syncthreads();
    if (threadIdx.x == 0) {
        atomicAdd(out, wsum[0] + wsum[1] + wsum[2] + wsum[3]);
    }
}

extern "C" void kernel_launch(void* const* d_in, const int* in_sizes, int n_in,
                              void* d_out, int out_size, void* d_ws, size_t ws_size,
                              hipStream_t stream) {
    const int* eb_input = (const int*)d_in[0];   // int32 indices
    // d_in[1] = eb_offset: mathematically irrelevant (result sums over all bags).
    const float* W0 = (const float*)d_in[2];
    const float* W1 = (const float*)d_in[3];
    const float* W2 = (const float*)d_in[4];

    const int N = in_sizes[0];
    const int nrows = in_sizes[2] / EB_D;   // V = 100000

    float* rowsum = (float*)d_ws;           // V floats = 400 KB
    float* out = (float*)d_out;

    hipMemsetAsync(out, 0, (size_t)out_size * sizeof(float), stream);

    // Kernel 1: 32 rows per block.
    const int blocks1 = (nrows + 31) / 32;  // 3125
    eb_rowsum_kernel<<<blocks1, 256, 0, stream>>>(W0, W1, W2, rowsum, nrows);

    // Kernel 2: vectorized gather-reduce.
    const int n4 = N / 4;
    int blocks2 = (n4 + 255) / 256;
    if (blocks2 > 1024) blocks2 = 1024;
    eb_gather_reduce_kernel<<<blocks2, 256, 0, stream>>>(
        eb_input, rowsum, out, n4, N, nrows);
}

// Round 6
// 46.234 us; speedup vs baseline: 1.8020x; 1.0615x over previous
//
#include <hip/hip_runtime.h>

#define EB_D 128

// Native vector types acceptable to __builtin_nontemporal_load
typedef float fx4 __attribute__((ext_vector_type(4)));
typedef int   ix4 __attribute__((ext_vector_type(4)));

// Kernel 1: rowsum[v] = 5*sum(W0[v,:]) + 10*sum(W1[v,:]) + 6*sum(W2[v,:])
// Block = 256 threads = 4 waves; block owns 32 consecutive rows.
// Each wave handles 8 rows as 4 unrolled row-pairs; 12 independent
// NONTEMPORAL float4 loads in flight per thread (tables are read-once:
// bypass L2/L3 allocation, stream straight from HBM).
__global__ __launch_bounds__(256) void eb_rowsum_kernel(
    const float* __restrict__ W0,
    const float* __restrict__ W1,
    const float* __restrict__ W2,
    float* __restrict__ rowsum,
    int nrows)
{
    const int lane   = threadIdx.x & 63;
    const int wave   = threadIdx.x >> 6;          // 0..3
    const int lane32 = lane & 31;
    const int half   = lane >> 5;                 // 0/1: which row of the pair
    const int rbase  = blockIdx.x * 32 + wave * 8 + half;  // rows rbase+2s, s=0..3

    fx4 a[4], b[4], c[4];
    #pragma unroll
    for (int s = 0; s < 4; ++s) {
        const int v = rbase + 2 * s;
        const size_t base = (size_t)v * EB_D;
        a[s] = __builtin_nontemporal_load((const fx4*)(W0 + base) + lane32);
        b[s] = __builtin_nontemporal_load((const fx4*)(W1 + base) + lane32);
        c[s] = __builtin_nontemporal_load((const fx4*)(W2 + base) + lane32);
    }

    #pragma unroll
    for (int s = 0; s < 4; ++s) {
        float sv = 5.0f  * (a[s].x + a[s].y + a[s].z + a[s].w)
                 + 10.0f * (b[s].x + b[s].y + b[s].z + b[s].w)
                 + 6.0f  * (c[s].x + c[s].y + c[s].z + c[s].w);
        // reduce across the 32 lanes of this half-wave
        #pragma unroll
        for (int m = 16; m >= 1; m >>= 1) sv += __shfl_xor(sv, m, 64);
        const int v = rbase + 2 * s;
        if (lane32 == 0 && v < nrows) rowsum[v] = sv;
    }
}

// Kernel 2: out += sum_i rowsum[idx[i]]  (idx int32); int4-vectorized.
// idx is read-once -> nontemporal; rowsum is hot (400 KB, L2) -> cached.
__global__ __launch_bounds__(256) void eb_gather_reduce_kernel(
    const int* __restrict__ idx,
    const float* __restrict__ rowsum,
    float* __restrict__ out,
    int n4, int n, int nrows)
{
    const int stride = gridDim.x * blockDim.x;
    const ix4* idx4 = (const ix4*)idx;
    float acc = 0.0f;
    for (int i = blockIdx.x * blockDim.x + threadIdx.x; i < n4; i += stride) {
        const ix4 v = __builtin_nontemporal_load(idx4 + i);
        float s0 = ((unsigned)v.x < (unsigned)nrows) ? rowsum[v.x] : 0.0f;
        float s1 = ((unsigned)v.y < (unsigned)nrows) ? rowsum[v.y] : 0.0f;
        float s2 = ((unsigned)v.z < (unsigned)nrows) ? rowsum[v.z] : 0.0f;
        float s3 = ((unsigned)v.w < (unsigned)nrows) ? rowsum[v.w] : 0.0f;
        acc += (s0 + s1) + (s2 + s3);
    }
    // tail (N % 4) — N=819200 divisible by 4, so this is a no-op here
    if (blockIdx.x == 0 && threadIdx.x < (n - n4 * 4)) {
        const int v = idx[n4 * 4 + threadIdx.x];
        if ((unsigned)v < (unsigned)nrows) acc += rowsum[v];
    }

    #pragma unroll
    for (int m = 32; m >= 1; m >>= 1) acc += __shfl_xor(acc, m, 64);

    __shared__ float wsum[4];
    const int lane = threadIdx.x & 63;
    const int wid  = threadIdx.x >> 6;
    if (lane == 0) wsum[wid] = acc;
    __syncthreads();
    if (threadIdx.x == 0) {
        atomicAdd(out, wsum[0] + wsum[1] + wsum[2] + wsum[3]);
    }
}

extern "C" void kernel_launch(void* const* d_in, const int* in_sizes, int n_in,
                              void* d_out, int out_size, void* d_ws, size_t ws_size,
                              hipStream_t stream) {
    const int* eb_input = (const int*)d_in[0];   // int32 indices
    // d_in[1] = eb_offset: mathematically irrelevant (result sums over all bags).
    const float* W0 = (const float*)d_in[2];
    const float* W1 = (const float*)d_in[3];
    const float* W2 = (const float*)d_in[4];

    const int N = in_sizes[0];
    const int nrows = in_sizes[2] / EB_D;   // V = 100000

    float* rowsum = (float*)d_ws;           // V floats = 400 KB
    float* out = (float*)d_out;

    (void)hipMemsetAsync(out, 0, (size_t)out_size * sizeof(float), stream);

    // Kernel 1: 32 rows per block.
    const int blocks1 = (nrows + 31) / 32;  // 3125
    eb_rowsum_kernel<<<blocks1, 256, 0, stream>>>(W0, W1, W2, rowsum, nrows);

    // Kernel 2: vectorized gather-reduce.
    const int n4 = N / 4;
    int blocks2 = (n4 + 255) / 256;
    if (blocks2 > 1024) blocks2 = 1024;
    eb_gather_reduce_kernel<<<blocks2, 256, 0, stream>>>(
        eb_input, rowsum, out, n4, N, nrows);
}